// Round 1
// baseline (590.069 us; speedup 1.0000x reference)
//
#include <hip/hip_runtime.h>
#include <stdint.h>

typedef unsigned short u16;
typedef __attribute__((ext_vector_type(8))) short short8;
typedef __attribute__((ext_vector_type(4))) float f32x4;
typedef __attribute__((ext_vector_type(4))) int i32x4;

#define EPSF 1e-5f

__device__ __forceinline__ u16 f2bf(float f) {
  uint32_t u = __float_as_uint(f);
  u += 0x7FFFu + ((u >> 16) & 1u);
  return (u16)(u >> 16);
}
__device__ __forceinline__ u16 sgnbf(float y) {
  return y > 0.f ? (u16)0x3F80 : (y < 0.f ? (u16)0xBF80 : (u16)0);
}

// ---------------- BN1 stats (x is NCHW f32: 32,128,64,64) ----------------
__global__ void bn1_stage1(const float* __restrict__ x, float* __restrict__ p1) {
  int c = blockIdx.x >> 2, s = blockIdx.x & 3;
  int tid = threadIdx.x;
  float sum = 0.f, sq = 0.f;
  for (int n = s * 8; n < s * 8 + 8; ++n) {
    const f32x4* bp = (const f32x4*)(x + (((size_t)(n * 128 + c)) << 12));
    #pragma unroll 4
    for (int i = tid; i < 1024; i += 256) {
      f32x4 v = bp[i];
      sum += v[0] + v[1] + v[2] + v[3];
      sq  += v[0]*v[0] + v[1]*v[1] + v[2]*v[2] + v[3]*v[3];
    }
  }
  __shared__ float rs[256], rq[256];
  rs[tid] = sum; rq[tid] = sq; __syncthreads();
  for (int st = 128; st > 0; st >>= 1) {
    if (tid < st) { rs[tid] += rs[tid + st]; rq[tid] += rq[tid + st]; }
    __syncthreads();
  }
  if (tid == 0) { p1[blockIdx.x] = rs[0]; p1[512 + blockIdx.x] = rq[0]; }
}

__global__ void bn1_stage2(const float* __restrict__ p1, const float* __restrict__ g,
                           const float* __restrict__ b, float* __restrict__ sc,
                           float* __restrict__ off) {
  int c = threadIdx.x; // 128 threads
  float s = 0.f, q = 0.f;
  for (int k = 0; k < 4; ++k) { s += p1[c * 4 + k]; q += p1[512 + c * 4 + k]; }
  float mean = s * (1.f / 131072.f);
  float var  = q * (1.f / 131072.f) - mean * mean;
  float is = rsqrtf(var + EPSF);
  float scv = g[c] * is;
  sc[c] = scv;
  off[c] = b[c] - mean * scv;
}

// ---------------- BN2 stats (h is [131072][256] f32 row-major) ----------------
__global__ void bn2_stage1(const float* __restrict__ h, float* __restrict__ p2) {
  int tid = threadIdx.x;
  float s = 0.f, q = 0.f;
  #pragma unroll 4
  for (int r = blockIdx.x; r < 131072; r += 256) {
    float v = h[(size_t)r * 256 + tid];
    s += v; q += v * v;
  }
  p2[blockIdx.x * 256 + tid] = s;
  p2[65536 + blockIdx.x * 256 + tid] = q;
}

__global__ void bn2_stage2(const float* __restrict__ p2, const float* __restrict__ g,
                           const float* __restrict__ b, float* __restrict__ sc,
                           float* __restrict__ off) {
  int c = threadIdx.x; // 256 threads
  float s = 0.f, q = 0.f;
  for (int k = 0; k < 256; ++k) { s += p2[k * 256 + c]; q += p2[65536 + k * 256 + c]; }
  float mean = s * (1.f / 131072.f);
  float var  = q * (1.f / 131072.f) - mean * mean;
  float is = rsqrtf(var + EPSF);
  float scv = g[c] * is;
  sc[c] = scv;
  off[c] = b[c] - mean * scv;
}

// ---------------- weight prep ----------------
__device__ __forceinline__ float blk_reduce(float v, float* red) {
  int t = threadIdx.x;
  red[t] = v; __syncthreads();
  for (int st = 128; st > 0; st >>= 1) {
    if (t < st) red[t] += red[t + st];
    __syncthreads();
  }
  float r = red[0]; __syncthreads();
  return r;
}

// w1cat[o][tap*128+c] = sign(w1[o][c][tap]) as bf16 +-1 ; alpha1[o] = mean|w1[o]|
// w2cat[o][tap*256+c] = sign(w2)            ; w2cat[o][2304+c] = sign(wskip)*alphask/alpha2
__global__ void prep_weights(const float* __restrict__ w1, const float* __restrict__ w2,
                             const float* __restrict__ wsk, u16* __restrict__ w1cat,
                             u16* __restrict__ w2cat, float* __restrict__ alpha1,
                             float* __restrict__ alpha2) {
  int o = blockIdx.x, t = threadIdx.x;
  __shared__ float red[256];
  // alpha1
  float s = 0.f;
  for (int j = t; j < 1152; j += 256) s += fabsf(w1[(size_t)o * 1152 + j]);
  float a1 = blk_reduce(s, red) * (1.f / 1152.f);
  if (t == 0) alpha1[o] = a1;
  for (int j = t; j < 1152; j += 256) {
    int tap = j >> 7, c = j & 127;
    float w = w1[(size_t)o * 1152 + c * 9 + tap];
    w1cat[(size_t)o * 1152 + j] = sgnbf(w);
  }
  // alpha2
  s = 0.f;
  for (int j = t; j < 2304; j += 256) s += fabsf(w2[(size_t)o * 2304 + j]);
  float a2 = blk_reduce(s, red) * (1.f / 2304.f);
  if (t == 0) alpha2[o] = a2;
  for (int j = t; j < 2304; j += 256) {
    int tap = j >> 8, c = j & 255;
    float w = w2[(size_t)o * 2304 + c * 9 + tap];
    w2cat[(size_t)o * 2432 + j] = sgnbf(w);
  }
  // skip: alphask, ratio-scaled signs appended as K-tail of w2cat
  s = 0.f;
  for (int j = t; j < 128; j += 256) s += fabsf(wsk[o * 128 + j]);
  float ask = blk_reduce(s, red) * (1.f / 128.f);
  float ratio = ask / a2;
  for (int j = t; j < 128; j += 256) {
    float w = wsk[o * 128 + j];
    float v = w > 0.f ? ratio : (w < 0.f ? -ratio : 0.f);
    w2cat[(size_t)o * 2432 + 2304 + j] = f2bf(v);
  }
}

// ---------------- temb = t @ tw^T + tb ----------------
__global__ void temb_k(const float* __restrict__ t, const float* __restrict__ tw,
                       const float* __restrict__ tb, float* __restrict__ temb) {
  int bb = blockIdx.x, o = threadIdx.x;
  __shared__ float tl[512];
  tl[o] = t[bb * 512 + o];
  tl[o + 256] = t[bb * 512 + 256 + o];
  __syncthreads();
  float acc = tb[o];
  #pragma unroll 8
  for (int k = 0; k < 512; ++k) acc += tl[k] * tw[(size_t)o * 512 + k];
  temb[bb * 256 + o] = acc;
}

// ---------------- binact1: x NCHW -> a1p padded NHWC bf16 signs + xb NHWC bf16 ----------------
__global__ void binact1(const float* __restrict__ x, const float* __restrict__ sc,
                        const float* __restrict__ off, u16* __restrict__ a1p,
                        u16* __restrict__ xb) {
  int b = blockIdx.x >> 6, y = blockIdx.x & 63, tid = threadIdx.x;
  __shared__ u16 ls[64 * 136];
  __shared__ u16 lx[64 * 136];
  int c = tid >> 1, x0 = (tid & 1) * 32;
  const float* src = x + (((size_t)(b * 128 + c)) << 12) + y * 64 + x0;
  float s0 = sc[c], o0 = off[c];
  #pragma unroll
  for (int i = 0; i < 32; i += 4) {
    f32x4 v = *(const f32x4*)(src + i);
    #pragma unroll
    for (int j = 0; j < 4; ++j) {
      int xc = x0 + i + j;
      float yv = s0 * v[j] + o0;
      ls[xc * 136 + c] = sgnbf(yv);
      lx[xc * 136 + c] = f2bf(v[j]);
    }
  }
  __syncthreads();
  int xx = tid >> 2, cg = (tid & 3) * 32;
  u16* pdst = a1p + ((((size_t)b * 66 + y + 1) * 66) + xx + 1) * 128 + cg;
  u16* xdst = xb + ((size_t)blockIdx.x * 64 + xx) * 128 + cg;
  #pragma unroll
  for (int i = 0; i < 32; i += 8) {
    *(i32x4*)(pdst + i) = *(const i32x4*)&ls[xx * 136 + cg + i];
    *(i32x4*)(xdst + i) = *(const i32x4*)&lx[xx * 136 + cg + i];
  }
}

// ---------------- binact2: h [m][256] f32 -> a2p padded NHWC bf16 signs ----------------
__global__ void binact2(const float* __restrict__ h, const float* __restrict__ sc,
                        const float* __restrict__ off, u16* __restrict__ a2p) {
  int b = blockIdx.x >> 6, y = blockIdx.x & 63, tid = threadIdx.x;
  __shared__ float s_sc[256], s_off[256];
  s_sc[tid] = sc[tid]; s_off[tid] = off[tid];
  __syncthreads();
  const f32x4* src = (const f32x4*)(h + (size_t)blockIdx.x * 16384);
  u16* dst = a2p + (((size_t)b * 66 + y + 1) * 66 + 1) * 256;
  #pragma unroll 4
  for (int i = tid; i < 4096; i += 256) {
    f32x4 v = src[i];
    int c0 = (i * 4) & 255;
    u16 r0 = sgnbf(s_sc[c0 + 0] * v[0] + s_off[c0 + 0]);
    u16 r1 = sgnbf(s_sc[c0 + 1] * v[1] + s_off[c0 + 1]);
    u16 r2 = sgnbf(s_sc[c0 + 2] * v[2] + s_off[c0 + 2]);
    u16 r3 = sgnbf(s_sc[c0 + 3] * v[3] + s_off[c0 + 3]);
    uint32_t lo = (uint32_t)r0 | ((uint32_t)r1 << 16);
    uint32_t hi = (uint32_t)r2 | ((uint32_t)r3 << 16);
    uint2 pack; pack.x = lo; pack.y = hi;
    *(uint2*)(dst + i * 4) = pack;
  }
}

// ---------------- implicit-GEMM conv (128x128 tile, BK=64, 4 waves) ----------------
// A: padded NHWC sign buffer (CH channels, 9 taps) [+ EXTRA channels from Xtra per row]
// B: Wcat [256][9*CH+EXTRA] bf16
// out[m][o] = alpha[o] * acc (+ temb[b][o])
template <int CH, int EXTRA, bool ADD_TEMB>
__global__ __launch_bounds__(256, 2) void convk(
    const u16* __restrict__ Apad, const u16* __restrict__ Xtra,
    const u16* __restrict__ Wcat, const float* __restrict__ alpha,
    const float* __restrict__ temb, float* __restrict__ outp) {
  constexpr int KT = 9 * CH + EXTRA;
  constexpr int NSTEP = KT / 64;
  constexpr int CPS = CH / 64; // ch-steps per tap
  int m0 = blockIdx.x * 128, o0 = blockIdx.y * 128;
  int tid = threadIdx.x;
  int lane = tid & 63, w = tid >> 6;
  int wm = w >> 1, wn = w & 1;
  __shared__ u16 lA[128 * 64];
  __shared__ u16 lB[128 * 64];

  int r0 = tid >> 3, cc = tid & 7;
  size_t pb[4];
  int mrow[4];
  #pragma unroll
  for (int j = 0; j < 4; ++j) {
    int m = m0 + r0 + 32 * j;
    mrow[j] = m;
    int bb = m >> 12, yy = (m >> 6) & 63, xx = m & 63;
    pb[j] = (size_t)(bb * 66 + yy) * 66 + xx;
  }

  f32x4 acc[4][4] = {};

  for (int s = 0; s < NSTEP; ++s) {
    __syncthreads();
    // stage A tile [128 rows][64 ch]
    if (EXTRA == 0 || s < 9 * CPS) {
      int tap = s / CPS, ch0 = (s % CPS) * 64;
      int dy = tap / 3, dx = tap - dy * 3;
      size_t toff = (size_t)(dy * 66 + dx);
      #pragma unroll
      for (int j = 0; j < 4; ++j) {
        const u16* src = Apad + (pb[j] + toff) * CH + ch0 + cc * 8;
        *(i32x4*)&lA[(r0 + 32 * j) * 64 + cc * 8] = *(const i32x4*)src;
      }
    } else {
      int ch0 = (s - 9 * CPS) * 64;
      #pragma unroll
      for (int j = 0; j < 4; ++j) {
        const u16* src = Xtra + (size_t)mrow[j] * EXTRA + ch0 + cc * 8;
        *(i32x4*)&lA[(r0 + 32 * j) * 64 + cc * 8] = *(const i32x4*)src;
      }
    }
    // stage B tile [128 o-rows][64 k]
    #pragma unroll
    for (int j = 0; j < 4; ++j) {
      int orow = r0 + 32 * j;
      const u16* src = Wcat + (size_t)(o0 + orow) * KT + s * 64 + cc * 8;
      *(i32x4*)&lB[orow * 64 + cc * 8] = *(const i32x4*)src;
    }
    __syncthreads();
    // compute: 2 k-slices x 4x4 fragments
    short8 af[2][4], bfr[2][4];
    int arow = wm * 64 + (lane & 15);
    int brow = wn * 64 + (lane & 15);
    int kk = 8 * (lane >> 4);
    #pragma unroll
    for (int ks = 0; ks < 2; ++ks) {
      #pragma unroll
      for (int f = 0; f < 4; ++f) {
        af[ks][f]  = *(const short8*)&lA[(arow + f * 16) * 64 + ks * 32 + kk];
        bfr[ks][f] = *(const short8*)&lB[(brow + f * 16) * 64 + ks * 32 + kk];
      }
    }
    #pragma unroll
    for (int ks = 0; ks < 2; ++ks)
      #pragma unroll
      for (int mf = 0; mf < 4; ++mf)
        #pragma unroll
        for (int nf = 0; nf < 4; ++nf)
          acc[mf][nf] = __builtin_amdgcn_mfma_f32_16x16x32_bf16(
              af[ks][mf], bfr[ks][nf], acc[mf][nf], 0, 0, 0);
  }

  // epilogue: D col = lane&15, row = 4*(lane>>4)+reg
  int rbase = wm * 64 + 4 * (lane >> 4);
  int cbase = o0 + wn * 64 + (lane & 15);
  #pragma unroll
  for (int nf = 0; nf < 4; ++nf) {
    int o = cbase + nf * 16;
    float al = alpha[o];
    #pragma unroll
    for (int mf = 0; mf < 4; ++mf) {
      #pragma unroll
      for (int r = 0; r < 4; ++r) {
        int m = m0 + rbase + mf * 16 + r;
        float v = acc[mf][nf][r] * al;
        if (ADD_TEMB) v += temb[(m >> 12) * 256 + o];
        outp[(size_t)m * 256 + o] = v;
      }
    }
  }
}

// ---------------- NHWC -> NCHW output transpose ----------------
__global__ void transpose_out(const float* __restrict__ h2, float* __restrict__ out) {
  int b = blockIdx.x >> 6, y = blockIdx.x & 63, tid = threadIdx.x;
  __shared__ float ld[64 * 260];
  const f32x4* src = (const f32x4*)(h2 + (size_t)blockIdx.x * 16384);
  #pragma unroll
  for (int i = 0; i < 16; ++i) {
    int f = tid + 256 * i;
    f32x4 v = src[f];
    int e = f * 4;
    int x = e >> 8, o = e & 255;
    *(f32x4*)&ld[x * 260 + o] = v;
  }
  __syncthreads();
  int x = tid & 63, oo = tid >> 6;
  #pragma unroll 4
  for (int j = 0; j < 64; ++j) {
    int o = j * 4 + oo;
    out[(((size_t)(b * 256 + o)) * 64 + y) * 64 + x] = ld[x * 260 + o];
  }
}

extern "C" void kernel_launch(void* const* d_in, const int* in_sizes, int n_in,
                              void* d_out, int out_size, void* d_ws, size_t ws_size,
                              hipStream_t stream) {
  const float* x      = (const float*)d_in[0];
  const float* t      = (const float*)d_in[1];
  const float* w1     = (const float*)d_in[2];
  const float* w2     = (const float*)d_in[3];
  const float* wskip  = (const float*)d_in[4];
  const float* gamma1 = (const float*)d_in[5];
  const float* beta1  = (const float*)d_in[6];
  const float* gamma2 = (const float*)d_in[7];
  const float* beta2  = (const float*)d_in[8];
  const float* tw     = (const float*)d_in[9];
  const float* tb     = (const float*)d_in[10];
  float* out = (float*)d_out;

  uint8_t* base = (uint8_t*)d_ws;
  size_t off = 0;
  auto alloc = [&](size_t bytes) {
    void* p = base + off;
    off += (bytes + 255) & ~(size_t)255;
    return p;
  };
  const size_t szApad = (size_t)32 * 66 * 66 * 256 * 2; // union a1p/a2p
  u16* Apad    = (u16*)alloc(szApad);
  u16* xb      = (u16*)alloc((size_t)131072 * 128 * 2);
  float* h     = (float*)alloc((size_t)131072 * 256 * 4);
  u16* w1cat   = (u16*)alloc((size_t)256 * 1152 * 2);
  u16* w2cat   = (u16*)alloc((size_t)256 * 2432 * 2);
  float* temb  = (float*)alloc(32 * 256 * 4);
  float* alpha1 = (float*)alloc(256 * 4);
  float* alpha2 = (float*)alloc(256 * 4);
  float* p1    = (float*)alloc(1024 * 4);
  float* p2    = (float*)alloc(131072 * 4);
  float* sc1   = (float*)alloc(128 * 4);
  float* off1  = (float*)alloc(128 * 4);
  float* sc2   = (float*)alloc(256 * 4);
  float* off2  = (float*)alloc(256 * 4);

  // zero padded buffer (borders for a1p)
  hipMemsetAsync(Apad, 0, szApad, stream);

  bn1_stage1<<<512, 256, 0, stream>>>(x, p1);
  bn1_stage2<<<1, 128, 0, stream>>>(p1, gamma1, beta1, sc1, off1);
  prep_weights<<<256, 256, 0, stream>>>(w1, w2, wskip, w1cat, w2cat, alpha1, alpha2);
  temb_k<<<32, 256, 0, stream>>>(t, tw, tb, temb);
  binact1<<<2048, 256, 0, stream>>>(x, sc1, off1, Apad, xb);

  convk<128, 0, true><<<dim3(1024, 2), 256, 0, stream>>>(Apad, (const u16*)nullptr,
                                                         w1cat, alpha1, temb, h);

  bn2_stage1<<<256, 256, 0, stream>>>(h, p2);
  bn2_stage2<<<1, 256, 0, stream>>>(p2, gamma2, beta2, sc2, off2);

  // re-zero padded buffer (borders for a2p; a1p no longer needed)
  hipMemsetAsync(Apad, 0, szApad, stream);
  binact2<<<2048, 256, 0, stream>>>(h, sc2, off2, Apad);

  convk<256, 128, false><<<dim3(1024, 2), 256, 0, stream>>>(Apad, xb, w2cat, alpha2,
                                                            (const float*)nullptr, h);

  transpose_out<<<2048, 256, 0, stream>>>(h, out);
  (void)in_sizes; (void)n_in; (void)out_size; (void)ws_size;
}

// Round 2
// 570.018 us; speedup vs baseline: 1.0352x; 1.0352x over previous
//
#include <hip/hip_runtime.h>
#include <stdint.h>

typedef unsigned short u16;
typedef __attribute__((ext_vector_type(8))) short short8;
typedef __attribute__((ext_vector_type(4))) float f32x4;
typedef __attribute__((ext_vector_type(4))) int i32x4;

#define EPSF 1e-5f

__device__ __forceinline__ u16 f2bf(float f) {
  uint32_t u = __float_as_uint(f);
  u += 0x7FFFu + ((u >> 16) & 1u);
  return (u16)(u >> 16);
}
__device__ __forceinline__ u16 sgnbf(float y) {
  return y > 0.f ? (u16)0x3F80 : (y < 0.f ? (u16)0xBF80 : (u16)0);
}

// ---------------- BN1 stats (x is NCHW f32: 32,128,64,64) ----------------
__global__ void bn1_stage1(const float* __restrict__ x, float* __restrict__ p1) {
  int c = blockIdx.x >> 2, s = blockIdx.x & 3;
  int tid = threadIdx.x;
  float sum = 0.f, sq = 0.f;
  for (int n = s * 8; n < s * 8 + 8; ++n) {
    const f32x4* bp = (const f32x4*)(x + (((size_t)(n * 128 + c)) << 12));
    #pragma unroll 4
    for (int i = tid; i < 1024; i += 256) {
      f32x4 v = bp[i];
      sum += v[0] + v[1] + v[2] + v[3];
      sq  += v[0]*v[0] + v[1]*v[1] + v[2]*v[2] + v[3]*v[3];
    }
  }
  __shared__ float rs[256], rq[256];
  rs[tid] = sum; rq[tid] = sq; __syncthreads();
  for (int st = 128; st > 0; st >>= 1) {
    if (tid < st) { rs[tid] += rs[tid + st]; rq[tid] += rq[tid + st]; }
    __syncthreads();
  }
  if (tid == 0) { p1[blockIdx.x] = rs[0]; p1[512 + blockIdx.x] = rq[0]; }
}

__global__ void bn1_stage2(const float* __restrict__ p1, const float* __restrict__ g,
                           const float* __restrict__ b, float* __restrict__ sc,
                           float* __restrict__ off) {
  int c = threadIdx.x; // 128 threads
  float s = 0.f, q = 0.f;
  for (int k = 0; k < 4; ++k) { s += p1[c * 4 + k]; q += p1[512 + c * 4 + k]; }
  float mean = s * (1.f / 131072.f);
  float var  = q * (1.f / 131072.f) - mean * mean;
  float is = rsqrtf(var + EPSF);
  float scv = g[c] * is;
  sc[c] = scv;
  off[c] = b[c] - mean * scv;
}

// ---------------- BN2 stats (h is [131072][256] f32 row-major) ----------------
__global__ void bn2_stage1(const float* __restrict__ h, float* __restrict__ p2) {
  int tid = threadIdx.x;
  float s = 0.f, q = 0.f;
  #pragma unroll 4
  for (int r = blockIdx.x; r < 131072; r += 256) {
    float v = h[(size_t)r * 256 + tid];
    s += v; q += v * v;
  }
  p2[blockIdx.x * 256 + tid] = s;
  p2[65536 + blockIdx.x * 256 + tid] = q;
}

__global__ void bn2_stage2(const float* __restrict__ p2, const float* __restrict__ g,
                           const float* __restrict__ b, float* __restrict__ sc,
                           float* __restrict__ off) {
  int c = threadIdx.x; // 256 threads
  float s = 0.f, q = 0.f;
  for (int k = 0; k < 256; ++k) { s += p2[k * 256 + c]; q += p2[65536 + k * 256 + c]; }
  float mean = s * (1.f / 131072.f);
  float var  = q * (1.f / 131072.f) - mean * mean;
  float is = rsqrtf(var + EPSF);
  float scv = g[c] * is;
  sc[c] = scv;
  off[c] = b[c] - mean * scv;
}

// ---------------- weight prep ----------------
__device__ __forceinline__ float blk_reduce(float v, float* red) {
  int t = threadIdx.x;
  red[t] = v; __syncthreads();
  for (int st = 128; st > 0; st >>= 1) {
    if (t < st) red[t] += red[t + st];
    __syncthreads();
  }
  float r = red[0]; __syncthreads();
  return r;
}

// Pre-swizzled weight step-blocks: wS[step][o][64] u16, element (o,k) stored at
// o*64 + (k ^ ((o&7)<<3)).  conv1: step = cc*9+tap (cc<2). conv2: cc<4 taps,
// then steps 36,37 = skip (sign(wskip)*alpha_sk/alpha2).
__global__ void prep_weights(const float* __restrict__ w1, const float* __restrict__ w2,
                             const float* __restrict__ wsk, u16* __restrict__ w1s,
                             u16* __restrict__ w2s, float* __restrict__ alpha1,
                             float* __restrict__ alpha2) {
  int o = blockIdx.x, t = threadIdx.x;
  __shared__ float red[256];
  float s = 0.f;
  for (int j = t; j < 1152; j += 256) s += fabsf(w1[(size_t)o * 1152 + j]);
  float a1 = blk_reduce(s, red) * (1.f / 1152.f);
  if (t == 0) alpha1[o] = a1;
  for (int j = t; j < 1152; j += 256) {
    int st = j >> 6, k = j & 63;
    int cc = st / 9, tap = st % 9;
    int c = cc * 64 + k;
    float w = w1[(size_t)o * 1152 + c * 9 + tap];
    w1s[(size_t)st * 16384 + o * 64 + (k ^ ((o & 7) << 3))] = sgnbf(w);
  }
  s = 0.f;
  for (int j = t; j < 2304; j += 256) s += fabsf(w2[(size_t)o * 2304 + j]);
  float a2 = blk_reduce(s, red) * (1.f / 2304.f);
  if (t == 0) alpha2[o] = a2;
  for (int j = t; j < 2304; j += 256) {
    int st = j >> 6, k = j & 63;
    int cc = st / 9, tap = st % 9;
    int c = cc * 64 + k;
    float w = w2[(size_t)o * 2304 + c * 9 + tap];
    w2s[(size_t)st * 16384 + o * 64 + (k ^ ((o & 7) << 3))] = sgnbf(w);
  }
  s = 0.f;
  for (int j = t; j < 128; j += 256) s += fabsf(wsk[o * 128 + j]);
  float ask = blk_reduce(s, red) * (1.f / 128.f);
  float ratio = ask / a2;
  for (int j = t; j < 128; j += 256) {
    int e = j >> 6, k = j & 63;
    float w = wsk[o * 128 + j];
    float v = w > 0.f ? ratio : (w < 0.f ? -ratio : 0.f);
    w2s[(size_t)(36 + e) * 16384 + o * 64 + (k ^ ((o & 7) << 3))] = f2bf(v);
  }
}

// ---------------- temb = t @ tw^T + tb ----------------
__global__ void temb_k(const float* __restrict__ t, const float* __restrict__ tw,
                       const float* __restrict__ tb, float* __restrict__ temb) {
  int bb = blockIdx.x, o = threadIdx.x;
  __shared__ float tl[512];
  tl[o] = t[bb * 512 + o];
  tl[o + 256] = t[bb * 512 + 256 + o];
  __syncthreads();
  float acc = tb[o];
  #pragma unroll 8
  for (int k = 0; k < 512; ++k) acc += tl[k] * tw[(size_t)o * 512 + k];
  temb[bb * 256 + o] = acc;
}

// -------- binact1: x NCHW -> a1p planes [b][cc=2][66][66][64] + xb [m][128] --------
__global__ void binact1(const float* __restrict__ x, const float* __restrict__ sc,
                        const float* __restrict__ off, u16* __restrict__ a1p,
                        u16* __restrict__ xb) {
  int b = blockIdx.x >> 6, y = blockIdx.x & 63, tid = threadIdx.x;
  __shared__ u16 ls[64 * 136];
  __shared__ u16 lx[64 * 136];
  int c = tid >> 1, x0 = (tid & 1) * 32;
  const float* src = x + (((size_t)(b * 128 + c)) << 12) + y * 64 + x0;
  float s0 = sc[c], o0 = off[c];
  #pragma unroll
  for (int i = 0; i < 32; i += 4) {
    f32x4 v = *(const f32x4*)(src + i);
    #pragma unroll
    for (int j = 0; j < 4; ++j) {
      int xc = x0 + i + j;
      float yv = s0 * v[j] + o0;
      ls[xc * 136 + c] = sgnbf(yv);
      lx[xc * 136 + c] = f2bf(v[j]);
    }
  }
  __syncthreads();
  int xx = tid >> 2, cg = (tid & 3) * 32;
  int cc = cg >> 6, ch0 = cg & 63;
  u16* pdst = a1p + (((size_t)(b * 2 + cc) * 66 + y + 1) * 66 + xx + 1) * 64 + ch0;
  u16* xdst = xb + ((size_t)blockIdx.x * 64 + xx) * 128 + cg;
  #pragma unroll
  for (int i = 0; i < 32; i += 8) {
    *(i32x4*)(pdst + i) = *(const i32x4*)&ls[xx * 136 + cg + i];
    *(i32x4*)(xdst + i) = *(const i32x4*)&lx[xx * 136 + cg + i];
  }
}

// -------- binact2: h [m][256] f32 -> a2p planes [b][cc=4][66][66][64] --------
__global__ void binact2(const float* __restrict__ h, const float* __restrict__ sc,
                        const float* __restrict__ off, u16* __restrict__ a2p) {
  int b = blockIdx.x >> 6, y = blockIdx.x & 63, tid = threadIdx.x;
  __shared__ float s_sc[256], s_off[256];
  s_sc[tid] = sc[tid]; s_off[tid] = off[tid];
  __syncthreads();
  const f32x4* src = (const f32x4*)(h + (size_t)blockIdx.x * 16384);
  #pragma unroll 4
  for (int i = tid; i < 4096; i += 256) {
    f32x4 v = src[i];
    int e = i * 4;
    int xx = e >> 8, c0 = e & 255;
    int cc = c0 >> 6, ch = c0 & 63;
    u16 r0 = sgnbf(s_sc[c0 + 0] * v[0] + s_off[c0 + 0]);
    u16 r1 = sgnbf(s_sc[c0 + 1] * v[1] + s_off[c0 + 1]);
    u16 r2 = sgnbf(s_sc[c0 + 2] * v[2] + s_off[c0 + 2]);
    u16 r3 = sgnbf(s_sc[c0 + 3] * v[3] + s_off[c0 + 3]);
    uint32_t lo = (uint32_t)r0 | ((uint32_t)r1 << 16);
    uint32_t hi = (uint32_t)r2 | ((uint32_t)r3 << 16);
    uint2 pack; pack.x = lo; pack.y = hi;
    u16* dst = a2p + (((size_t)(b * 4 + cc) * 66 + y + 1) * 66 + xx + 1) * 64 + ch;
    *(uint2*)dst = pack;
  }
}

// ---------------- window-staged implicit-GEMM conv ----------------
// M-tile = 128 rows (2 image rows), N = 256 (full), 512 threads = 8 waves (2M x 4N).
// A: halo window [4 rows][66 px][64 ch] in LDS (XOR-swizzled), staged once per
//    ch-chunk; 9 taps are LDS offsets. Extra chunks (conv2 skip) staged from Xtra.
// B: pre-swizzled weight step-blocks [256][64], double-buffered global_load_lds.
template <int CPS, int NEXTRA, bool ADD_TEMB>
__global__ __launch_bounds__(512, 2) void convk(
    const u16* __restrict__ Apad, const u16* __restrict__ Xtra,
    const u16* __restrict__ wS, const float* __restrict__ alpha,
    const float* __restrict__ temb, float* __restrict__ outp) {
  constexpr int NSTEP = 9 * CPS + NEXTRA;
  __shared__ u16 lA[4 * 66 * 64];     // 33792 B
  __shared__ u16 lB[2][256 * 64];     // 2 x 32768 B
  int tid = threadIdx.x;
  int lane = tid & 63, w = tid >> 6, wm = w >> 2, wn = w & 3;
  int kq = lane >> 4, li = lane & 15;

  int bid = blockIdx.x;
  int tile = (bid & 7) * 128 + (bid >> 3);   // XCD-chunked swizzle (1024 % 8 == 0)
  int m0 = tile * 128;
  int b = m0 >> 12, row0 = (m0 >> 6) & 63;

  auto issueB = [&](int s) {
    const u16* g = wS + (size_t)s * 16384 + tid * 8;
    u16* l = (u16*)&lB[s & 1][(tid & 448) * 8];
    #pragma unroll
    for (int r = 0; r < 4; ++r)
      __builtin_amdgcn_global_load_lds(
          (const __attribute__((address_space(1))) void*)(g + r * 4096),
          (__attribute__((address_space(3))) void*)(l + r * 4096), 16, 0, 0);
  };

  i32x4 wrA, wrB, wrC, wrD, wrE;

  auto winG = [&](int c, int i) -> const i32x4* {
    const u16* gp = Apad + ((size_t)(b * CPS + c) * 66 + row0) * 4224;
    return (const i32x4*)(gp + i * 8);
  };
  auto winL = [&](int i) -> i32x4* {
    int row = i / 528, offn = i - row * 528;
    int px = offn >> 3, c16 = offn & 7;
    return (i32x4*)&lA[(row * 66 + px) * 64 + ((c16 * 8) ^ ((px & 7) << 3))];
  };
  auto extG = [&](int e, int i) -> const i32x4* {
    int ml = i >> 3, c16 = i & 7;
    return (const i32x4*)(Xtra + (size_t)(m0 + ml) * 128 + e * 64 + c16 * 8);
  };
  auto extL = [&](int i) -> i32x4* {
    int ml = i >> 3, c16 = i & 7;
    int wrow = ml >> 6, p = (ml & 63) + 1;
    return (i32x4*)&lA[(wrow * 66 + p) * 64 + ((c16 * 8) ^ ((p & 7) << 3))];
  };

  auto loadWin = [&](int c) {
    if (c < CPS) {
      wrA = *winG(c, tid);
      wrB = *winG(c, tid + 512);
      wrC = *winG(c, tid + 1024);
      wrD = *winG(c, tid + 1536);
      if (tid < 64) wrE = *winG(c, tid + 2048);
    } else {
      int e = c - CPS;
      wrA = *extG(e, tid);
      wrB = *extG(e, tid + 512);
    }
  };
  auto writeWin = [&](int c) {
    if (c < CPS) {
      *winL(tid) = wrA;
      *winL(tid + 512) = wrB;
      *winL(tid + 1024) = wrC;
      *winL(tid + 1536) = wrD;
      if (tid < 64) *winL(tid + 2048) = wrE;
    } else {
      *extL(tid) = wrA;
      *extL(tid + 512) = wrB;
    }
  };
  auto chunkOf = [&](int s) { return s < 9 * CPS ? s / 9 : CPS + (s - 9 * CPS); };

  f32x4 acc[4][4] = {};

  issueB(0);
  loadWin(0);
  __syncthreads();
  writeWin(0);
  __syncthreads();

  for (int s = 0; s < NSTEP; ++s) {
    if (s + 1 < NSTEP) issueB(s + 1);
    int cn = (s + 1 < NSTEP) ? chunkOf(s + 1) : -1;
    bool bnd = (cn >= 0) && (cn != chunkOf(s));
    if (bnd) loadWin(cn);

    int dy, dx;
    if (s < 9 * CPS) { int tap = s % 9; dy = tap / 3; dx = tap % 3; }
    else { dy = 0; dx = 1; }

    const u16* bbuf = lB[s & 1];
    short8 af[2][4], bfv[2][4];
    #pragma unroll
    for (int ks = 0; ks < 2; ++ks) {
      #pragma unroll
      for (int f = 0; f < 4; ++f) {
        int p = f * 16 + li + dx;
        af[ks][f] = *(const short8*)&lA[((wm + dy) * 66 + p) * 64 +
                                        ((ks * 32 + kq * 8) ^ ((p & 7) << 3))];
        int ol = wn * 64 + f * 16 + li;
        bfv[ks][f] = *(const short8*)&bbuf[ol * 64 +
                                           ((ks * 32 + kq * 8) ^ ((ol & 7) << 3))];
      }
    }
    #pragma unroll
    for (int ks = 0; ks < 2; ++ks)
      #pragma unroll
      for (int mf = 0; mf < 4; ++mf)
        #pragma unroll
        for (int nf = 0; nf < 4; ++nf)
          acc[mf][nf] = __builtin_amdgcn_mfma_f32_16x16x32_bf16(
              af[ks][mf], bfv[ks][nf], acc[mf][nf], 0, 0, 0);

    __syncthreads();
    if (bnd) { writeWin(cn); __syncthreads(); }
  }

  // epilogue: D col = lane&15 (o), row = 4*(lane>>4)+reg (m)
  int rb = wm * 64 + 4 * kq;
  int cb = wn * 64 + li;
  #pragma unroll
  for (int nf = 0; nf < 4; ++nf) {
    int o = cb + nf * 16;
    float al = alpha[o];
    float ta = 0.f;
    if (ADD_TEMB) ta = temb[b * 256 + o];
    #pragma unroll
    for (int mf = 0; mf < 4; ++mf) {
      #pragma unroll
      for (int r = 0; r < 4; ++r) {
        int m = m0 + rb + mf * 16 + r;
        outp[(size_t)m * 256 + o] = acc[mf][nf][r] * al + ta;
      }
    }
  }
}

// ---------------- NHWC -> NCHW output transpose ----------------
__global__ void transpose_out(const float* __restrict__ h2, float* __restrict__ out) {
  int b = blockIdx.x >> 6, y = blockIdx.x & 63, tid = threadIdx.x;
  __shared__ float ld[64 * 260];
  const f32x4* src = (const f32x4*)(h2 + (size_t)blockIdx.x * 16384);
  #pragma unroll
  for (int i = 0; i < 16; ++i) {
    int f = tid + 256 * i;
    f32x4 v = src[f];
    int e = f * 4;
    int x = e >> 8, o = e & 255;
    *(f32x4*)&ld[x * 260 + o] = v;
  }
  __syncthreads();
  int x = tid & 63, oo = tid >> 6;
  #pragma unroll 4
  for (int j = 0; j < 64; ++j) {
    int o = j * 4 + oo;
    out[(((size_t)(b * 256 + o)) * 64 + y) * 64 + x] = ld[x * 260 + o];
  }
}

extern "C" void kernel_launch(void* const* d_in, const int* in_sizes, int n_in,
                              void* d_out, int out_size, void* d_ws, size_t ws_size,
                              hipStream_t stream) {
  const float* x      = (const float*)d_in[0];
  const float* t      = (const float*)d_in[1];
  const float* w1     = (const float*)d_in[2];
  const float* w2     = (const float*)d_in[3];
  const float* wskip  = (const float*)d_in[4];
  const float* gamma1 = (const float*)d_in[5];
  const float* beta1  = (const float*)d_in[6];
  const float* gamma2 = (const float*)d_in[7];
  const float* beta2  = (const float*)d_in[8];
  const float* tw     = (const float*)d_in[9];
  const float* tb     = (const float*)d_in[10];
  float* out = (float*)d_out;

  uint8_t* base = (uint8_t*)d_ws;
  size_t off = 0;
  auto alloc = [&](size_t bytes) {
    void* p = base + off;
    off += (bytes + 255) & ~(size_t)255;
    return p;
  };
  const size_t szApad = (size_t)32 * 4 * 66 * 66 * 64 * 2; // 128 planes of [66][66][64]
  u16* Apad    = (u16*)alloc(szApad);
  u16* xb      = (u16*)alloc((size_t)131072 * 128 * 2);
  float* h     = (float*)alloc((size_t)131072 * 256 * 4);
  u16* w1s     = (u16*)alloc((size_t)18 * 16384 * 2);
  u16* w2s     = (u16*)alloc((size_t)38 * 16384 * 2);
  float* temb  = (float*)alloc(32 * 256 * 4);
  float* alpha1 = (float*)alloc(256 * 4);
  float* alpha2 = (float*)alloc(256 * 4);
  float* p1    = (float*)alloc(1024 * 4);
  float* p2    = (float*)alloc(131072 * 4);
  float* sc1   = (float*)alloc(128 * 4);
  float* off1  = (float*)alloc(128 * 4);
  float* sc2   = (float*)alloc(256 * 4);
  float* off2  = (float*)alloc(256 * 4);

  // zero padded planes once: binact1/binact2 only write interiors, borders stay 0
  hipMemsetAsync(Apad, 0, szApad, stream);

  bn1_stage1<<<512, 256, 0, stream>>>(x, p1);
  bn1_stage2<<<1, 128, 0, stream>>>(p1, gamma1, beta1, sc1, off1);
  prep_weights<<<256, 256, 0, stream>>>(w1, w2, wskip, w1s, w2s, alpha1, alpha2);
  temb_k<<<32, 256, 0, stream>>>(t, tw, tb, temb);
  binact1<<<2048, 256, 0, stream>>>(x, sc1, off1, Apad, xb);

  convk<2, 0, true><<<1024, 512, 0, stream>>>(Apad, xb, w1s, alpha1, temb, h);

  bn2_stage1<<<256, 256, 0, stream>>>(h, p2);
  bn2_stage2<<<1, 256, 0, stream>>>(p2, gamma2, beta2, sc2, off2);
  binact2<<<2048, 256, 0, stream>>>(h, sc2, off2, Apad);

  convk<4, 2, false><<<1024, 512, 0, stream>>>(Apad, xb, w2s, alpha2,
                                               (const float*)nullptr, h);

  transpose_out<<<2048, 256, 0, stream>>>(h, out);
  (void)in_sizes; (void)n_in; (void)out_size; (void)ws_size;
}

// Round 3
// 501.506 us; speedup vs baseline: 1.1766x; 1.1366x over previous
//
#include <hip/hip_runtime.h>
#include <stdint.h>

typedef unsigned short u16;
typedef __attribute__((ext_vector_type(8))) short short8;
typedef __attribute__((ext_vector_type(4))) float f32x4;
typedef __attribute__((ext_vector_type(4))) int i32x4;

#define EPSF 1e-5f

__device__ __forceinline__ u16 f2bf(float f) {
  uint32_t u = __float_as_uint(f);
  u += 0x7FFFu + ((u >> 16) & 1u);
  return (u16)(u >> 16);
}
__device__ __forceinline__ u16 sgnbf(float y) {
  return y > 0.f ? (u16)0x3F80 : (y < 0.f ? (u16)0xBF80 : (u16)0);
}

// ---------------- BN1 stats (x is NCHW f32: 32,128,64,64) ----------------
__global__ void bn1_stage1(const float* __restrict__ x, float* __restrict__ p1) {
  int c = blockIdx.x >> 2, s = blockIdx.x & 3;
  int tid = threadIdx.x;
  float sum = 0.f, sq = 0.f;
  for (int n = s * 8; n < s * 8 + 8; ++n) {
    const f32x4* bp = (const f32x4*)(x + (((size_t)(n * 128 + c)) << 12));
    #pragma unroll 4
    for (int i = tid; i < 1024; i += 256) {
      f32x4 v = bp[i];
      sum += v[0] + v[1] + v[2] + v[3];
      sq  += v[0]*v[0] + v[1]*v[1] + v[2]*v[2] + v[3]*v[3];
    }
  }
  __shared__ float rs[256], rq[256];
  rs[tid] = sum; rq[tid] = sq; __syncthreads();
  for (int st = 128; st > 0; st >>= 1) {
    if (tid < st) { rs[tid] += rs[tid + st]; rq[tid] += rq[tid + st]; }
    __syncthreads();
  }
  if (tid == 0) { p1[blockIdx.x] = rs[0]; p1[512 + blockIdx.x] = rq[0]; }
}

__global__ void bn1_stage2(const float* __restrict__ p1, const float* __restrict__ g,
                           const float* __restrict__ b, float* __restrict__ sc,
                           float* __restrict__ off) {
  int c = threadIdx.x; // 128 threads
  float s = 0.f, q = 0.f;
  for (int k = 0; k < 4; ++k) { s += p1[c * 4 + k]; q += p1[512 + c * 4 + k]; }
  float mean = s * (1.f / 131072.f);
  float var  = q * (1.f / 131072.f) - mean * mean;
  float is = rsqrtf(var + EPSF);
  float scv = g[c] * is;
  sc[c] = scv;
  off[c] = b[c] - mean * scv;
}

// ---------------- BN2 stats (h is [131072][256] f32 row-major) ----------------
__global__ void bn2_stage1(const float* __restrict__ h, float* __restrict__ p2) {
  int tid = threadIdx.x;
  float s = 0.f, q = 0.f;
  #pragma unroll 4
  for (int r = blockIdx.x; r < 131072; r += 256) {
    float v = h[(size_t)r * 256 + tid];
    s += v; q += v * v;
  }
  p2[blockIdx.x * 256 + tid] = s;
  p2[65536 + blockIdx.x * 256 + tid] = q;
}

__global__ void bn2_stage2(const float* __restrict__ p2, const float* __restrict__ g,
                           const float* __restrict__ b, float* __restrict__ sc,
                           float* __restrict__ off) {
  int c = threadIdx.x; // 256 threads
  float s = 0.f, q = 0.f;
  for (int k = 0; k < 256; ++k) { s += p2[k * 256 + c]; q += p2[65536 + k * 256 + c]; }
  float mean = s * (1.f / 131072.f);
  float var  = q * (1.f / 131072.f) - mean * mean;
  float is = rsqrtf(var + EPSF);
  float scv = g[c] * is;
  sc[c] = scv;
  off[c] = b[c] - mean * scv;
}

// ---------------- weight prep ----------------
__device__ __forceinline__ float blk_reduce(float v, float* red) {
  int t = threadIdx.x;
  red[t] = v; __syncthreads();
  for (int st = 128; st > 0; st >>= 1) {
    if (t < st) red[t] += red[t + st];
    __syncthreads();
  }
  float r = red[0]; __syncthreads();
  return r;
}

// Pre-swizzled weight step-blocks: wS[step][o][64] u16, element (o,k) stored at
// o*64 + (k ^ ((o&7)<<3)).  conv1: step = cc*9+tap (cc<2). conv2: cc<4 taps,
// then steps 36,37 = skip (sign(wskip)*alpha_sk/alpha2).
__global__ void prep_weights(const float* __restrict__ w1, const float* __restrict__ w2,
                             const float* __restrict__ wsk, u16* __restrict__ w1s,
                             u16* __restrict__ w2s, float* __restrict__ alpha1,
                             float* __restrict__ alpha2) {
  int o = blockIdx.x, t = threadIdx.x;
  __shared__ float red[256];
  float s = 0.f;
  for (int j = t; j < 1152; j += 256) s += fabsf(w1[(size_t)o * 1152 + j]);
  float a1 = blk_reduce(s, red) * (1.f / 1152.f);
  if (t == 0) alpha1[o] = a1;
  for (int j = t; j < 1152; j += 256) {
    int st = j >> 6, k = j & 63;
    int cc = st / 9, tap = st % 9;
    int c = cc * 64 + k;
    float w = w1[(size_t)o * 1152 + c * 9 + tap];
    w1s[(size_t)st * 16384 + o * 64 + (k ^ ((o & 7) << 3))] = sgnbf(w);
  }
  s = 0.f;
  for (int j = t; j < 2304; j += 256) s += fabsf(w2[(size_t)o * 2304 + j]);
  float a2 = blk_reduce(s, red) * (1.f / 2304.f);
  if (t == 0) alpha2[o] = a2;
  for (int j = t; j < 2304; j += 256) {
    int st = j >> 6, k = j & 63;
    int cc = st / 9, tap = st % 9;
    int c = cc * 64 + k;
    float w = w2[(size_t)o * 2304 + c * 9 + tap];
    w2s[(size_t)st * 16384 + o * 64 + (k ^ ((o & 7) << 3))] = sgnbf(w);
  }
  s = 0.f;
  for (int j = t; j < 128; j += 256) s += fabsf(wsk[o * 128 + j]);
  float ask = blk_reduce(s, red) * (1.f / 128.f);
  float ratio = ask / a2;
  for (int j = t; j < 128; j += 256) {
    int e = j >> 6, k = j & 63;
    float w = wsk[o * 128 + j];
    float v = w > 0.f ? ratio : (w < 0.f ? -ratio : 0.f);
    w2s[(size_t)(36 + e) * 16384 + o * 64 + (k ^ ((o & 7) << 3))] = f2bf(v);
  }
}

// ---------------- temb = t @ tw^T + tb ----------------
__global__ void temb_k(const float* __restrict__ t, const float* __restrict__ tw,
                       const float* __restrict__ tb, float* __restrict__ temb) {
  int bb = blockIdx.x, o = threadIdx.x;
  __shared__ float tl[512];
  tl[o] = t[bb * 512 + o];
  tl[o + 256] = t[bb * 512 + 256 + o];
  __syncthreads();
  float acc = tb[o];
  #pragma unroll 8
  for (int k = 0; k < 512; ++k) acc += tl[k] * tw[(size_t)o * 512 + k];
  temb[bb * 256 + o] = acc;
}

// ---------------- border zero: 128 planes of [66][66][64], borders only ----------------
__global__ void border_zero(u16* __restrict__ Apad) {
  u16* plane = Apad + (size_t)blockIdx.x * 66 * 66 * 64;
  int tid = threadIdx.x;
  i32x4 z = {};
  for (int idx = tid; idx < 260; idx += 256) {
    int row, px;
    if (idx < 66) { row = 0; px = idx; }
    else if (idx < 132) { row = 65; px = idx - 66; }
    else { int e = idx - 132; row = 1 + (e >> 1); px = (e & 1) * 65; }
    u16* p = plane + (row * 66 + px) * 64;
    #pragma unroll
    for (int i = 0; i < 8; ++i) *(i32x4*)(p + i * 8) = z;
  }
}

// -------- binact1: x NCHW -> a1p planes [b][cc=2][66][66][64] + xb [m][128] --------
__global__ void binact1(const float* __restrict__ x, const float* __restrict__ sc,
                        const float* __restrict__ off, u16* __restrict__ a1p,
                        u16* __restrict__ xb) {
  int b = blockIdx.x >> 6, y = blockIdx.x & 63, tid = threadIdx.x;
  __shared__ u16 ls[64 * 136];
  __shared__ u16 lx[64 * 136];
  int c = tid >> 1, x0 = (tid & 1) * 32;
  const float* src = x + (((size_t)(b * 128 + c)) << 12) + y * 64 + x0;
  float s0 = sc[c], o0 = off[c];
  #pragma unroll
  for (int i = 0; i < 32; i += 4) {
    f32x4 v = *(const f32x4*)(src + i);
    #pragma unroll
    for (int j = 0; j < 4; ++j) {
      int xc = x0 + i + j;
      float yv = s0 * v[j] + o0;
      ls[xc * 136 + c] = sgnbf(yv);
      lx[xc * 136 + c] = f2bf(v[j]);
    }
  }
  __syncthreads();
  int xx = tid >> 2, cg = (tid & 3) * 32;
  int cc = cg >> 6, ch0 = cg & 63;
  u16* pdst = a1p + (((size_t)(b * 2 + cc) * 66 + y + 1) * 66 + xx + 1) * 64 + ch0;
  u16* xdst = xb + ((size_t)blockIdx.x * 64 + xx) * 128 + cg;
  #pragma unroll
  for (int i = 0; i < 32; i += 8) {
    *(i32x4*)(pdst + i) = *(const i32x4*)&ls[xx * 136 + cg + i];
    *(i32x4*)(xdst + i) = *(const i32x4*)&lx[xx * 136 + cg + i];
  }
}

// -------- binact2: h [m][256] f32 -> a2p planes [b][cc=4][66][66][64] --------
__global__ void binact2(const float* __restrict__ h, const float* __restrict__ sc,
                        const float* __restrict__ off, u16* __restrict__ a2p) {
  int b = blockIdx.x >> 6, y = blockIdx.x & 63, tid = threadIdx.x;
  __shared__ float s_sc[256], s_off[256];
  s_sc[tid] = sc[tid]; s_off[tid] = off[tid];
  __syncthreads();
  const f32x4* src = (const f32x4*)(h + (size_t)blockIdx.x * 16384);
  #pragma unroll 4
  for (int i = tid; i < 4096; i += 256) {
    f32x4 v = src[i];
    int e = i * 4;
    int xx = e >> 8, c0 = e & 255;
    int cc = c0 >> 6, ch = c0 & 63;
    u16 r0 = sgnbf(s_sc[c0 + 0] * v[0] + s_off[c0 + 0]);
    u16 r1 = sgnbf(s_sc[c0 + 1] * v[1] + s_off[c0 + 1]);
    u16 r2 = sgnbf(s_sc[c0 + 2] * v[2] + s_off[c0 + 2]);
    u16 r3 = sgnbf(s_sc[c0 + 3] * v[3] + s_off[c0 + 3]);
    uint32_t lo = (uint32_t)r0 | ((uint32_t)r1 << 16);
    uint32_t hi = (uint32_t)r2 | ((uint32_t)r3 << 16);
    uint2 pack; pack.x = lo; pack.y = hi;
    u16* dst = a2p + (((size_t)(b * 4 + cc) * 66 + y + 1) * 66 + xx + 1) * 64 + ch;
    *(uint2*)dst = pack;
  }
}

// ---------------- window-staged implicit-GEMM conv, T3/T4/T5 schedule ----------------
// M-tile = 128 rows (2 image rows), N = 256 (full), 512 threads = 8 waves (2M x 4N).
// A: halo window [4 rows][66 px][64 ch] in LDS (XOR-swizzled), staged once per
//    ch-chunk; 9 taps are LDS offsets. Extra chunks (conv2 skip) staged from Xtra.
// B: pre-swizzled weight step-blocks [256][64], double-buffered global_load_lds,
//    counted vmcnt(4) (prefetch stays in flight across the step), raw s_barrier.
template <int CPS, int NEXTRA, bool ADD_TEMB>
__global__ __launch_bounds__(512, 2) void convk(
    const u16* __restrict__ Apad, const u16* __restrict__ Xtra,
    const u16* __restrict__ wS, const float* __restrict__ alpha,
    const float* __restrict__ temb, float* __restrict__ outp) {
  constexpr int NSTEP = 9 * CPS + NEXTRA;
  __shared__ u16 lA[4 * 66 * 64];     // 33792 B
  __shared__ u16 lB[2][256 * 64];     // 2 x 32768 B
  const int tid = threadIdx.x;
  const int lane = tid & 63, w = tid >> 6, wm = w >> 2, wn = w & 3;
  const int kq = lane >> 4, li = lane & 15;

  const int bid = blockIdx.x;
  const int tile = (bid & 7) * 128 + (bid >> 3);   // XCD-chunked swizzle
  const int m0 = tile * 128;
  const int b = m0 >> 12, row0 = (m0 >> 6) & 63;

  auto issueB = [&](int s) {
    const u16* g = wS + (size_t)s * 16384 + tid * 8;
    u16* l = (u16*)&lB[s & 1][(tid & 448) * 8];
    #pragma unroll
    for (int r = 0; r < 4; ++r)
      __builtin_amdgcn_global_load_lds(
          (const __attribute__((address_space(1))) void*)(g + r * 4096),
          (__attribute__((address_space(3))) void*)(l + r * 4096), 16, 0, 0);
  };

  i32x4 wrA, wrB, wrC, wrD, wrE;

  auto winG = [&](int c, int i) -> const i32x4* {
    const u16* gp = Apad + ((size_t)(b * CPS + c) * 66 + row0) * 4224;
    return (const i32x4*)(gp + i * 8);
  };
  auto winL = [&](int i) -> i32x4* {
    int row = i / 528, offn = i - row * 528;
    int px = offn >> 3, c16 = offn & 7;
    return (i32x4*)&lA[(row * 66 + px) * 64 + ((c16 * 8) ^ ((px & 7) << 3))];
  };
  auto extG = [&](int e, int i) -> const i32x4* {
    int ml = i >> 3, c16 = i & 7;
    return (const i32x4*)(Xtra + (size_t)(m0 + ml) * 128 + e * 64 + c16 * 8);
  };
  auto extL = [&](int i) -> i32x4* {
    int ml = i >> 3, c16 = i & 7;
    int wrow = ml >> 6, p = (ml & 63) + 1;
    return (i32x4*)&lA[(wrow * 66 + p) * 64 + ((c16 * 8) ^ ((p & 7) << 3))];
  };
  auto loadWin = [&](int c) {
    if (c < CPS) {
      wrA = *winG(c, tid);
      wrB = *winG(c, tid + 512);
      wrC = *winG(c, tid + 1024);
      wrD = *winG(c, tid + 1536);
      if (tid < 64) wrE = *winG(c, tid + 2048);
    } else {
      int e = c - CPS;
      wrA = *extG(e, tid);
      wrB = *extG(e, tid + 512);
    }
  };
  auto writeWin = [&](int c) {
    if (c < CPS) {
      *winL(tid) = wrA;
      *winL(tid + 512) = wrB;
      *winL(tid + 1024) = wrC;
      *winL(tid + 1536) = wrD;
      if (tid < 64) *winL(tid + 2048) = wrE;
    } else {
      *extL(tid) = wrA;
      *extL(tid + 512) = wrB;
    }
  };

  // Precomputed swizzled fragment base pointers (per-step addressing = imm offsets)
  const u16* pA[3][2];
  #pragma unroll
  for (int dx = 0; dx < 3; ++dx)
    #pragma unroll
    for (int ks = 0; ks < 2; ++ks)
      pA[dx][ks] = &lA[wm * 4224 + (li + dx) * 64 +
                       ((ks * 32 + kq * 8) ^ (((li + dx) & 7) << 3))];
  const u16* pB[2];
  #pragma unroll
  for (int ks = 0; ks < 2; ++ks)
    pB[ks] = &lB[0][(wn * 64 + li) * 64 + ((ks * 32 + kq * 8) ^ ((li & 7) << 3))];

  f32x4 acc[4][4] = {};

  // prologue: B(0) + window chunk 0
  issueB(0);
  loadWin(0);
  asm volatile("s_waitcnt vmcnt(0)" ::: "memory");
  __builtin_amdgcn_s_barrier();
  writeWin(0);
  asm volatile("s_waitcnt lgkmcnt(0)" ::: "memory");
  __builtin_amdgcn_s_barrier();

  #pragma unroll
  for (int s = 0; s < NSTEP; ++s) {
    if (s + 1 < NSTEP) {
      issueB(s + 1);
      asm volatile("s_waitcnt vmcnt(4)" ::: "memory");  // my B(s) loads landed
    } else {
      asm volatile("s_waitcnt vmcnt(0)" ::: "memory");
    }
    __builtin_amdgcn_s_barrier();   // everyone's B(s) landed; lB[s&1] readable

    const int cs = (s < 9 * CPS) ? (s / 9) : (CPS + (s - 9 * CPS));
    const int cn = ((s + 1) < 9 * CPS) ? ((s + 1) / 9) : (CPS + (s + 1 - 9 * CPS));
    const bool bnd = (s + 1 < NSTEP) && (cn != cs);
    if (bnd) loadWin(cn);   // global->reg, consumed after the end-of-step fence

    int dy, dx;
    if (s < 9 * CPS) { int tap = s % 9; dy = tap / 3; dx = tap % 3; }
    else { dy = 0; dx = 1; }

    short8 af[2][4], bfv[2][4];
    #pragma unroll
    for (int ks = 0; ks < 2; ++ks)
      #pragma unroll
      for (int f = 0; f < 4; ++f) {
        af[ks][f]  = *(const short8*)(pA[dx][ks] + dy * 4224 + f * 1024);
        bfv[ks][f] = *(const short8*)(pB[ks] + (s & 1) * 16384 + f * 1024);
      }
    __builtin_amdgcn_s_setprio(1);
    #pragma unroll
    for (int ks = 0; ks < 2; ++ks)
      #pragma unroll
      for (int mf = 0; mf < 4; ++mf)
        #pragma unroll
        for (int nf = 0; nf < 4; ++nf)
          acc[mf][nf] = __builtin_amdgcn_mfma_f32_16x16x32_bf16(
              af[ks][mf], bfv[ks][nf], acc[mf][nf], 0, 0, 0);
    __builtin_amdgcn_s_setprio(0);

    // my LDS reads data-complete -> after barrier, next-step gload_lds may overwrite
    asm volatile("s_waitcnt lgkmcnt(0)" ::: "memory");
    __builtin_amdgcn_s_barrier();

    if (bnd) {
      writeWin(cn);
      asm volatile("s_waitcnt lgkmcnt(0)" ::: "memory");
      __builtin_amdgcn_s_barrier();
    }
  }

  // epilogue: D col = lane&15 (o), row = 4*(lane>>4)+reg (m)
  int rb = wm * 64 + 4 * kq;
  int cb = wn * 64 + li;
  #pragma unroll
  for (int nf = 0; nf < 4; ++nf) {
    int o = cb + nf * 16;
    float al = alpha[o];
    float ta = 0.f;
    if (ADD_TEMB) ta = temb[b * 256 + o];
    #pragma unroll
    for (int mf = 0; mf < 4; ++mf) {
      #pragma unroll
      for (int r = 0; r < 4; ++r) {
        int m = m0 + rb + mf * 16 + r;
        outp[(size_t)m * 256 + o] = acc[mf][nf][r] * al + ta;
      }
    }
  }
}

// ---------------- NHWC -> NCHW output transpose ----------------
__global__ void transpose_out(const float* __restrict__ h2, float* __restrict__ out) {
  int b = blockIdx.x >> 6, y = blockIdx.x & 63, tid = threadIdx.x;
  __shared__ float ld[64 * 260];
  const f32x4* src = (const f32x4*)(h2 + (size_t)blockIdx.x * 16384);
  #pragma unroll
  for (int i = 0; i < 16; ++i) {
    int f = tid + 256 * i;
    f32x4 v = src[f];
    int e = f * 4;
    int x = e >> 8, o = e & 255;
    *(f32x4*)&ld[x * 260 + o] = v;
  }
  __syncthreads();
  int x = tid & 63, oo = tid >> 6;
  #pragma unroll 4
  for (int j = 0; j < 64; ++j) {
    int o = j * 4 + oo;
    out[(((size_t)(b * 256 + o)) * 64 + y) * 64 + x] = ld[x * 260 + o];
  }
}

extern "C" void kernel_launch(void* const* d_in, const int* in_sizes, int n_in,
                              void* d_out, int out_size, void* d_ws, size_t ws_size,
                              hipStream_t stream) {
  const float* x      = (const float*)d_in[0];
  const float* t      = (const float*)d_in[1];
  const float* w1     = (const float*)d_in[2];
  const float* w2     = (const float*)d_in[3];
  const float* wskip  = (const float*)d_in[4];
  const float* gamma1 = (const float*)d_in[5];
  const float* beta1  = (const float*)d_in[6];
  const float* gamma2 = (const float*)d_in[7];
  const float* beta2  = (const float*)d_in[8];
  const float* tw     = (const float*)d_in[9];
  const float* tb     = (const float*)d_in[10];
  float* out = (float*)d_out;

  uint8_t* base = (uint8_t*)d_ws;
  size_t off = 0;
  auto alloc = [&](size_t bytes) {
    void* p = base + off;
    off += (bytes + 255) & ~(size_t)255;
    return p;
  };
  const size_t szApad = (size_t)32 * 4 * 66 * 66 * 64 * 2; // 128 planes of [66][66][64]
  u16* Apad    = (u16*)alloc(szApad);
  u16* xb      = (u16*)alloc((size_t)131072 * 128 * 2);
  float* h     = (float*)alloc((size_t)131072 * 256 * 4);
  u16* w1s     = (u16*)alloc((size_t)18 * 16384 * 2);
  u16* w2s     = (u16*)alloc((size_t)38 * 16384 * 2);
  float* temb  = (float*)alloc(32 * 256 * 4);
  float* alpha1 = (float*)alloc(256 * 4);
  float* alpha2 = (float*)alloc(256 * 4);
  float* p1    = (float*)alloc(1024 * 4);
  float* p2    = (float*)alloc(131072 * 4);
  float* sc1   = (float*)alloc(128 * 4);
  float* off1  = (float*)alloc(128 * 4);
  float* sc2   = (float*)alloc(256 * 4);
  float* off2  = (float*)alloc(256 * 4);

  // zero only the plane borders (binact1/binact2 write all interiors)
  border_zero<<<128, 256, 0, stream>>>(Apad);

  bn1_stage1<<<512, 256, 0, stream>>>(x, p1);
  bn1_stage2<<<1, 128, 0, stream>>>(p1, gamma1, beta1, sc1, off1);
  prep_weights<<<256, 256, 0, stream>>>(w1, w2, wskip, w1s, w2s, alpha1, alpha2);
  temb_k<<<32, 256, 0, stream>>>(t, tw, tb, temb);
  binact1<<<2048, 256, 0, stream>>>(x, sc1, off1, Apad, xb);

  convk<2, 0, true><<<1024, 512, 0, stream>>>(Apad, xb, w1s, alpha1, temb, h);

  bn2_stage1<<<256, 256, 0, stream>>>(h, p2);
  bn2_stage2<<<1, 256, 0, stream>>>(p2, gamma2, beta2, sc2, off2);
  binact2<<<2048, 256, 0, stream>>>(h, sc2, off2, Apad);

  convk<4, 2, false><<<1024, 512, 0, stream>>>(Apad, xb, w2s, alpha2,
                                               (const float*)nullptr, h);

  transpose_out<<<2048, 256, 0, stream>>>(h, out);
  (void)in_sizes; (void)n_in; (void)out_size; (void)ws_size;
}

// Round 4
// 441.948 us; speedup vs baseline: 1.3352x; 1.1348x over previous
//
#include <hip/hip_runtime.h>
#include <stdint.h>

typedef unsigned short u16;
typedef __attribute__((ext_vector_type(8))) short short8;
typedef __attribute__((ext_vector_type(4))) float f32x4;
typedef __attribute__((ext_vector_type(4))) int i32x4;

#define EPSF 1e-5f
#define LGKM0 asm volatile("s_waitcnt lgkmcnt(0)" ::: "memory")
#define VM0   asm volatile("s_waitcnt vmcnt(0)" ::: "memory")
#define BAR   __builtin_amdgcn_s_barrier()

__device__ __forceinline__ u16 f2bf(float f) {
  uint32_t u = __float_as_uint(f);
  u += 0x7FFFu + ((u >> 16) & 1u);
  return (u16)(u >> 16);
}
__device__ __forceinline__ u16 sgnbf(float y) {
  return y > 0.f ? (u16)0x3F80 : (y < 0.f ? (u16)0xBF80 : (u16)0);
}

// ---------------- BN1 stats (x is NCHW f32: 32,128,64,64) ----------------
__global__ void bn1_stage1(const float* __restrict__ x, float* __restrict__ p1) {
  int c = blockIdx.x >> 2, s = blockIdx.x & 3;
  int tid = threadIdx.x;
  float sum = 0.f, sq = 0.f;
  for (int n = s * 8; n < s * 8 + 8; ++n) {
    const f32x4* bp = (const f32x4*)(x + (((size_t)(n * 128 + c)) << 12));
    #pragma unroll 4
    for (int i = tid; i < 1024; i += 256) {
      f32x4 v = bp[i];
      sum += v[0] + v[1] + v[2] + v[3];
      sq  += v[0]*v[0] + v[1]*v[1] + v[2]*v[2] + v[3]*v[3];
    }
  }
  __shared__ float rs[256], rq[256];
  rs[tid] = sum; rq[tid] = sq; __syncthreads();
  for (int st = 128; st > 0; st >>= 1) {
    if (tid < st) { rs[tid] += rs[tid + st]; rq[tid] += rq[tid + st]; }
    __syncthreads();
  }
  if (tid == 0) { p1[blockIdx.x] = rs[0]; p1[512 + blockIdx.x] = rq[0]; }
}

__global__ void bn1_stage2(const float* __restrict__ p1, const float* __restrict__ g,
                           const float* __restrict__ b, float* __restrict__ sc,
                           float* __restrict__ off) {
  int c = threadIdx.x; // 128 threads
  float s = 0.f, q = 0.f;
  for (int k = 0; k < 4; ++k) { s += p1[c * 4 + k]; q += p1[512 + c * 4 + k]; }
  float mean = s * (1.f / 131072.f);
  float var  = q * (1.f / 131072.f) - mean * mean;
  float is = rsqrtf(var + EPSF);
  float scv = g[c] * is;
  sc[c] = scv;
  off[c] = b[c] - mean * scv;
}

// ---------------- BN2 stage2: reduce per-block partials from conv1 epilogue ----------------
__global__ void bn2_stage2b(const float* __restrict__ pS, const float* __restrict__ pQ,
                            const float* __restrict__ g, const float* __restrict__ bb,
                            float* __restrict__ sc, float* __restrict__ off) {
  int o = blockIdx.x, t = threadIdx.x;
  __shared__ float rs[256], rq[256];
  const float* ps = pS + (size_t)o * 1024;
  const float* pq = pQ + (size_t)o * 1024;
  float s = ps[t] + ps[t + 256] + ps[t + 512] + ps[t + 768];
  float q = pq[t] + pq[t + 256] + pq[t + 512] + pq[t + 768];
  rs[t] = s; rq[t] = q; __syncthreads();
  for (int st = 128; st > 0; st >>= 1) {
    if (t < st) { rs[t] += rs[t + st]; rq[t] += rq[t + st]; }
    __syncthreads();
  }
  if (t == 0) {
    float mean = rs[0] * (1.f / 131072.f);
    float var  = rq[0] * (1.f / 131072.f) - mean * mean;
    float is = rsqrtf(var + EPSF);
    float scv = g[o] * is;
    sc[o] = scv;
    off[o] = bb[o] - mean * scv;
  }
}

// ---------------- weight prep ----------------
__device__ __forceinline__ float blk_reduce(float v, float* red) {
  int t = threadIdx.x;
  red[t] = v; __syncthreads();
  for (int st = 128; st > 0; st >>= 1) {
    if (t < st) red[t] += red[t + st];
    __syncthreads();
  }
  float r = red[0]; __syncthreads();
  return r;
}

// Pre-swizzled weight step-blocks: wS[step][o][64] u16, element (o,k) stored at
// o*64 + (k ^ ((o&7)<<3)).  conv1: step = cc*9+tap (cc<2). conv2: cc<4 taps,
// then steps 36,37 = skip (sign(wskip)*alpha_sk/alpha2).
__global__ void prep_weights(const float* __restrict__ w1, const float* __restrict__ w2,
                             const float* __restrict__ wsk, u16* __restrict__ w1s,
                             u16* __restrict__ w2s, float* __restrict__ alpha1,
                             float* __restrict__ alpha2) {
  int o = blockIdx.x, t = threadIdx.x;
  __shared__ float red[256];
  float s = 0.f;
  for (int j = t; j < 1152; j += 256) s += fabsf(w1[(size_t)o * 1152 + j]);
  float a1 = blk_reduce(s, red) * (1.f / 1152.f);
  if (t == 0) alpha1[o] = a1;
  for (int j = t; j < 1152; j += 256) {
    int st = j >> 6, k = j & 63;
    int cc = st / 9, tap = st % 9;
    int c = cc * 64 + k;
    float w = w1[(size_t)o * 1152 + c * 9 + tap];
    w1s[(size_t)st * 16384 + o * 64 + (k ^ ((o & 7) << 3))] = sgnbf(w);
  }
  s = 0.f;
  for (int j = t; j < 2304; j += 256) s += fabsf(w2[(size_t)o * 2304 + j]);
  float a2 = blk_reduce(s, red) * (1.f / 2304.f);
  if (t == 0) alpha2[o] = a2;
  for (int j = t; j < 2304; j += 256) {
    int st = j >> 6, k = j & 63;
    int cc = st / 9, tap = st % 9;
    int c = cc * 64 + k;
    float w = w2[(size_t)o * 2304 + c * 9 + tap];
    w2s[(size_t)st * 16384 + o * 64 + (k ^ ((o & 7) << 3))] = sgnbf(w);
  }
  s = 0.f;
  for (int j = t; j < 128; j += 256) s += fabsf(wsk[o * 128 + j]);
  float ask = blk_reduce(s, red) * (1.f / 128.f);
  float ratio = ask / a2;
  for (int j = t; j < 128; j += 256) {
    int e = j >> 6, k = j & 63;
    float w = wsk[o * 128 + j];
    float v = w > 0.f ? ratio : (w < 0.f ? -ratio : 0.f);
    w2s[(size_t)(36 + e) * 16384 + o * 64 + (k ^ ((o & 7) << 3))] = f2bf(v);
  }
}

// ---------------- temb = t @ tw^T + tb ----------------
__global__ void temb_k(const float* __restrict__ t, const float* __restrict__ tw,
                       const float* __restrict__ tb, float* __restrict__ temb) {
  int bb = blockIdx.x, o = threadIdx.x;
  __shared__ float tl[512];
  tl[o] = t[bb * 512 + o];
  tl[o + 256] = t[bb * 512 + 256 + o];
  __syncthreads();
  float acc = tb[o];
  #pragma unroll 8
  for (int k = 0; k < 512; ++k) acc += tl[k] * tw[(size_t)o * 512 + k];
  temb[bb * 256 + o] = acc;
}

// ---------------- border zero: 128 planes of [66][66][64], borders only ----------------
__global__ void border_zero(u16* __restrict__ Apad) {
  u16* plane = Apad + (size_t)blockIdx.x * 66 * 66 * 64;
  int tid = threadIdx.x;
  i32x4 z = {};
  for (int idx = tid; idx < 260; idx += 256) {
    int row, px;
    if (idx < 66) { row = 0; px = idx; }
    else if (idx < 132) { row = 65; px = idx - 66; }
    else { int e = idx - 132; row = 1 + (e >> 1); px = (e & 1) * 65; }
    u16* p = plane + (row * 66 + px) * 64;
    #pragma unroll
    for (int i = 0; i < 8; ++i) *(i32x4*)(p + i * 8) = z;
  }
}

// -------- binact1: x NCHW -> a1p planes [b][cc=2][66][66][64] + xb [m][128] --------
__global__ void binact1(const float* __restrict__ x, const float* __restrict__ sc,
                        const float* __restrict__ off, u16* __restrict__ a1p,
                        u16* __restrict__ xb) {
  int b = blockIdx.x >> 6, y = blockIdx.x & 63, tid = threadIdx.x;
  __shared__ u16 ls[64 * 136];
  __shared__ u16 lx[64 * 136];
  int c = tid >> 1, x0 = (tid & 1) * 32;
  const float* src = x + (((size_t)(b * 128 + c)) << 12) + y * 64 + x0;
  float s0 = sc[c], o0 = off[c];
  #pragma unroll
  for (int i = 0; i < 32; i += 4) {
    f32x4 v = *(const f32x4*)(src + i);
    #pragma unroll
    for (int j = 0; j < 4; ++j) {
      int xc = x0 + i + j;
      float yv = s0 * v[j] + o0;
      ls[xc * 136 + c] = sgnbf(yv);
      lx[xc * 136 + c] = f2bf(v[j]);
    }
  }
  __syncthreads();
  int xx = tid >> 2, cg = (tid & 3) * 32;
  int cc = cg >> 6, ch0 = cg & 63;
  u16* pdst = a1p + (((size_t)(b * 2 + cc) * 66 + y + 1) * 66 + xx + 1) * 64 + ch0;
  u16* xdst = xb + ((size_t)blockIdx.x * 64 + xx) * 128 + cg;
  #pragma unroll
  for (int i = 0; i < 32; i += 8) {
    *(i32x4*)(pdst + i) = *(const i32x4*)&ls[xx * 136 + cg + i];
    *(i32x4*)(xdst + i) = *(const i32x4*)&lx[xx * 136 + cg + i];
  }
}

// -------- binact2: h [m][256] f32 -> a2p planes [b][cc=4][66][66][64] --------
__global__ void binact2(const float* __restrict__ h, const float* __restrict__ sc,
                        const float* __restrict__ off, u16* __restrict__ a2p) {
  int b = blockIdx.x >> 6, y = blockIdx.x & 63, tid = threadIdx.x;
  __shared__ float s_sc[256], s_off[256];
  s_sc[tid] = sc[tid]; s_off[tid] = off[tid];
  __syncthreads();
  const f32x4* src = (const f32x4*)(h + (size_t)blockIdx.x * 16384);
  #pragma unroll 4
  for (int i = tid; i < 4096; i += 256) {
    f32x4 v = src[i];
    int e = i * 4;
    int xx = e >> 8, c0 = e & 255;
    int cc = c0 >> 6, ch = c0 & 63;
    u16 r0 = sgnbf(s_sc[c0 + 0] * v[0] + s_off[c0 + 0]);
    u16 r1 = sgnbf(s_sc[c0 + 1] * v[1] + s_off[c0 + 1]);
    u16 r2 = sgnbf(s_sc[c0 + 2] * v[2] + s_off[c0 + 2]);
    u16 r3 = sgnbf(s_sc[c0 + 3] * v[3] + s_off[c0 + 3]);
    uint32_t lo = (uint32_t)r0 | ((uint32_t)r1 << 16);
    uint32_t hi = (uint32_t)r2 | ((uint32_t)r3 << 16);
    uint2 pack; pack.x = lo; pack.y = hi;
    u16* dst = a2p + (((size_t)(b * 4 + cc) * 66 + y + 1) * 66 + xx + 1) * 64 + ch;
    *(uint2*)dst = pack;
  }
}

// ---------------- window-staged implicit-GEMM conv ----------------
// M-tile = 128 rows, N = 256, 512 threads = 8 waves (2M x 4N). 2 blocks/CU.
// A: halo window [4][66][64] in LDS, XOR-swizzled via pre-swizzled-source
//    global_load_lds (linear dest), loaded once per ch-chunk in its dead zone.
// B: single 32 KB buffer, T14 reg-staged (global->reg at step start,
//    ds_write after the read barrier). No vmcnt(0) in steady-state loop.
// Epilogues: STATS -> write h + per-block BN2 partials; DIRECT -> LDS-transpose
//    and store NCHW straight to out.
template <int CPS, int NEXTRA, bool ADD_TEMB, bool STATS, bool DIRECT>
__global__ __launch_bounds__(512, 4) void convk(
    const u16* __restrict__ Apad, const u16* __restrict__ Xtra,
    const u16* __restrict__ wS, const float* __restrict__ alpha,
    const float* __restrict__ temb, float* __restrict__ outp,
    float* __restrict__ pS, float* __restrict__ pQ) {
  constexpr int NSTEP = 9 * CPS + NEXTRA;
  __shared__ u16 lA[4 * 66 * 64];     // 33792 B
  __shared__ u16 lB[256 * 64];        // 32768 B
  const int tid = threadIdx.x;
  const int lane = tid & 63, w = tid >> 6, wm = w >> 2, wn = w & 3;
  const int kq = lane >> 4, li = lane & 15;

  const int bid = blockIdx.x;
  const int tile = (bid & 7) * 128 + (bid >> 3);   // XCD-chunked swizzle
  const int m0 = tile * 128;
  const int b = m0 >> 12, row0 = (m0 >> 6) & 63;

  // ---- B stage: global (pre-swizzled) -> regs -> LDS linear ----
  i32x4 sB0, sB1, sB2, sB3;
  auto stageB = [&](int s) {
    const i32x4* g = (const i32x4*)(wS + (size_t)s * 16384) + tid;
    sB0 = g[0]; sB1 = g[512]; sB2 = g[1024]; sB3 = g[1536];
  };
  auto writeB = [&]() {
    i32x4* l = (i32x4*)lB + tid;
    l[0] = sB0; l[512] = sB1; l[1024] = sB2; l[1536] = sB3;
  };

  // ---- A window: global_load_lds, linear dest + pre-swizzled per-lane source ----
  auto winLoad = [&](int c) {
    const u16* gp = Apad + ((size_t)(b * CPS + c) * 66 + row0) * 4224;
    #pragma unroll
    for (int k = 0; k < 4; ++k) {
      int p = tid + k * 512;
      int row = p / 528, offn = p - row * 528;
      int px = offn >> 3, c16 = offn & 7;
      const u16* src = gp + (row * 66 + px) * 64 + ((c16 ^ (px & 7)) * 8);
      u16* ldst = lA + ((tid & ~63) + k * 512) * 8;
      __builtin_amdgcn_global_load_lds(
          (const __attribute__((address_space(1))) void*)src,
          (__attribute__((address_space(3))) void*)ldst, 16, 0, 0);
    }
    if (tid < 64) {
      int p = 2048 + tid;
      int row = p / 528, offn = p - row * 528;
      int px = offn >> 3, c16 = offn & 7;
      const u16* src = gp + (row * 66 + px) * 64 + ((c16 ^ (px & 7)) * 8);
      u16* ldst = lA + 2048 * 8;
      __builtin_amdgcn_global_load_lds(
          (const __attribute__((address_space(1))) void*)src,
          (__attribute__((address_space(3))) void*)ldst, 16, 0, 0);
    }
  };
  auto extLoad = [&](int e) {
    #pragma unroll
    for (int k = 0; k < 2; ++k) {
      int i = tid + k * 512;
      int ml = i >> 3, c16 = i & 7;
      int pp = (ml & 63) + 1;
      const u16* src = Xtra + (size_t)(m0 + ml) * 128 + e * 64 + ((c16 ^ (pp & 7)) * 8);
      u16* ldst = lA + (k * 66 + (tid >> 6) * 8 + 1) * 64;
      __builtin_amdgcn_global_load_lds(
          (const __attribute__((address_space(1))) void*)src,
          (__attribute__((address_space(3))) void*)ldst, 16, 0, 0);
    }
  };

  // ---- precomputed swizzled fragment base pointers ----
  const u16* pA[3][2];
  #pragma unroll
  for (int dx = 0; dx < 3; ++dx)
    #pragma unroll
    for (int ks = 0; ks < 2; ++ks)
      pA[dx][ks] = &lA[wm * 4224 + (li + dx) * 64 +
                       ((ks * 32 + kq * 8) ^ (((li + dx) & 7) << 3))];
  const u16* pB[2];
  #pragma unroll
  for (int ks = 0; ks < 2; ++ks)
    pB[ks] = &lB[(wn * 64 + li) * 64 + ((ks * 32 + kq * 8) ^ ((li & 7) << 3))];

  f32x4 acc[4][4] = {};

  auto compute = [&](int dy, int dx) {
    #pragma unroll
    for (int ks = 0; ks < 2; ++ks) {
      short8 af[4], bfv[4];
      #pragma unroll
      for (int f = 0; f < 4; ++f)
        af[f] = *(const short8*)(pA[dx][ks] + dy * 4224 + f * 1024);
      #pragma unroll
      for (int f = 0; f < 4; ++f)
        bfv[f] = *(const short8*)(pB[ks] + f * 1024);
      __builtin_amdgcn_s_setprio(1);
      #pragma unroll
      for (int mf = 0; mf < 4; ++mf)
        #pragma unroll
        for (int nf = 0; nf < 4; ++nf)
          acc[mf][nf] = __builtin_amdgcn_mfma_f32_16x16x32_bf16(
              af[mf], bfv[nf], acc[mf][nf], 0, 0, 0);
      __builtin_amdgcn_s_setprio(0);
    }
  };

  // ---- prologue ----
  stageB(0);
  winLoad(0);
  writeB();
  LGKM0; VM0; BAR;

  // ---- main loop ----
  #pragma unroll 1
  for (int c = 0; c < CPS; ++c) {
    #pragma unroll
    for (int tap = 0; tap < 9; ++tap) {
      const int s = c * 9 + tap;
      const bool last = (s == NSTEP - 1);
      if (!last) stageB(s + 1);
      compute(tap / 3, tap % 3);
      LGKM0; BAR;
      if (tap == 8 && !last) {
        if (c + 1 < CPS) winLoad(c + 1);
        else if constexpr (NEXTRA > 0) extLoad(0);
      }
      if (!last) {
        writeB();
        LGKM0;
        if (tap == 8) VM0;
        BAR;
      }
    }
  }
  if constexpr (NEXTRA > 0) {
    #pragma unroll
    for (int e = 0; e < NEXTRA; ++e) {
      const int s = 9 * CPS + e;
      const bool last = (s == NSTEP - 1);
      if (!last) stageB(s + 1);
      compute(0, 1);
      LGKM0; BAR;
      if (!last) {
        extLoad(e + 1);
        writeB();
        LGKM0; VM0; BAR;
      }
    }
  }
  LGKM0; BAR;   // LDS free for epilogue reuse

  const int rb = wm * 64 + 4 * kq;
  const int cb = wn * 64 + li;

  if constexpr (STATS) {
    // write h rows + accumulate per-block BN2 partials (deterministic)
    float ps[4] = {0.f, 0.f, 0.f, 0.f}, pq[4] = {0.f, 0.f, 0.f, 0.f};
    #pragma unroll
    for (int nf = 0; nf < 4; ++nf) {
      int o = cb + nf * 16;
      float al = alpha[o];
      float ta = ADD_TEMB ? temb[b * 256 + o] : 0.f;
      #pragma unroll
      for (int mf = 0; mf < 4; ++mf) {
        #pragma unroll
        for (int r = 0; r < 4; ++r) {
          int m = m0 + rb + mf * 16 + r;
          float v = acc[mf][nf][r] * al + ta;
          outp[(size_t)m * 256 + o] = v;
          ps[nf] += v; pq[nf] += v * v;
        }
      }
    }
    #pragma unroll
    for (int nf = 0; nf < 4; ++nf) {
      ps[nf] += __shfl_xor(ps[nf], 16); ps[nf] += __shfl_xor(ps[nf], 32);
      pq[nf] += __shfl_xor(pq[nf], 16); pq[nf] += __shfl_xor(pq[nf], 32);
    }
    float* reds = (float*)lA;          // [2][256]
    float* redq = reds + 512;
    if (lane < 16) {
      #pragma unroll
      for (int nf = 0; nf < 4; ++nf) {
        reds[wm * 256 + wn * 64 + nf * 16 + lane] = ps[nf];
        redq[wm * 256 + wn * 64 + nf * 16 + lane] = pq[nf];
      }
    }
    __syncthreads();
    if (tid < 256) {
      float s2 = reds[tid] + reds[256 + tid];
      float q2 = redq[tid] + redq[256 + tid];
      pS[(size_t)tid * 1024 + bid] = s2;
      pQ[(size_t)tid * 1024 + bid] = q2;
    }
  } else if constexpr (DIRECT) {
    // LDS transpose -> NCHW coalesced stores straight to out
    float* tb2 = (float*)lA;           // [128][65]
    const int o_l = tid >> 3, xs = (tid & 7) * 16;
    float* obase = outp + (((size_t)(b * 256)) << 12) + (m0 & 4095);
    #pragma unroll 1
    for (int c4 = 0; c4 < 4; ++c4) {
      if (wn == c4) {
        #pragma unroll
        for (int nf = 0; nf < 4; ++nf) {
          float al = alpha[cb + nf * 16];
          #pragma unroll
          for (int mf = 0; mf < 4; ++mf) {
            #pragma unroll
            for (int r = 0; r < 4; ++r)
              tb2[(rb + mf * 16 + r) * 65 + li + nf * 16] = acc[mf][nf][r] * al;
          }
        }
      }
      __syncthreads();
      float* dst = obase + (((size_t)(c4 * 64 + o_l)) << 12) + xs;
      #pragma unroll
      for (int q4 = 0; q4 < 4; ++q4) {
        f32x4 v;
        #pragma unroll
        for (int e = 0; e < 4; ++e) v[e] = tb2[(xs + q4 * 4 + e) * 65 + o_l];
        *(f32x4*)(dst + q4 * 4) = v;
      }
      __syncthreads();
    }
  }
}

extern "C" void kernel_launch(void* const* d_in, const int* in_sizes, int n_in,
                              void* d_out, int out_size, void* d_ws, size_t ws_size,
                              hipStream_t stream) {
  const float* x      = (const float*)d_in[0];
  const float* t      = (const float*)d_in[1];
  const float* w1     = (const float*)d_in[2];
  const float* w2     = (const float*)d_in[3];
  const float* wskip  = (const float*)d_in[4];
  const float* gamma1 = (const float*)d_in[5];
  const float* beta1  = (const float*)d_in[6];
  const float* gamma2 = (const float*)d_in[7];
  const float* beta2  = (const float*)d_in[8];
  const float* tw     = (const float*)d_in[9];
  const float* tb     = (const float*)d_in[10];
  float* out = (float*)d_out;

  uint8_t* base = (uint8_t*)d_ws;
  size_t off = 0;
  auto alloc = [&](size_t bytes) {
    void* p = base + off;
    off += (bytes + 255) & ~(size_t)255;
    return p;
  };
  const size_t szApad = (size_t)32 * 4 * 66 * 66 * 64 * 2; // 128 planes of [66][66][64]
  u16* Apad    = (u16*)alloc(szApad);
  u16* xb      = (u16*)alloc((size_t)131072 * 128 * 2);
  float* h     = (float*)alloc((size_t)131072 * 256 * 4);
  u16* w1s     = (u16*)alloc((size_t)18 * 16384 * 2);
  u16* w2s     = (u16*)alloc((size_t)38 * 16384 * 2);
  float* temb  = (float*)alloc(32 * 256 * 4);
  float* alpha1 = (float*)alloc(256 * 4);
  float* alpha2 = (float*)alloc(256 * 4);
  float* p1    = (float*)alloc(1024 * 4);
  float* pS    = (float*)alloc((size_t)256 * 1024 * 4);
  float* pQ    = (float*)alloc((size_t)256 * 1024 * 4);
  float* sc1   = (float*)alloc(128 * 4);
  float* off1  = (float*)alloc(128 * 4);
  float* sc2   = (float*)alloc(256 * 4);
  float* off2  = (float*)alloc(256 * 4);

  // zero only the plane borders (binact1/binact2 write all interiors)
  border_zero<<<128, 256, 0, stream>>>(Apad);

  bn1_stage1<<<512, 256, 0, stream>>>(x, p1);
  bn1_stage2<<<1, 128, 0, stream>>>(p1, gamma1, beta1, sc1, off1);
  prep_weights<<<256, 256, 0, stream>>>(w1, w2, wskip, w1s, w2s, alpha1, alpha2);
  temb_k<<<32, 256, 0, stream>>>(t, tw, tb, temb);
  binact1<<<2048, 256, 0, stream>>>(x, sc1, off1, Apad, xb);

  // conv1: writes h + BN2 per-block partials
  convk<2, 0, true, true, false><<<1024, 512, 0, stream>>>(
      Apad, xb, w1s, alpha1, temb, h, pS, pQ);

  bn2_stage2b<<<256, 256, 0, stream>>>(pS, pQ, gamma2, beta2, sc2, off2);
  binact2<<<2048, 256, 0, stream>>>(h, sc2, off2, Apad);

  // conv2: direct NCHW output (skip folded into K-tail)
  convk<4, 2, false, false, true><<<1024, 512, 0, stream>>>(
      Apad, xb, w2s, alpha2, (const float*)nullptr, out,
      (float*)nullptr, (float*)nullptr);

  (void)in_sizes; (void)n_in; (void)out_size; (void)ws_size;
}